// Round 1
// baseline (993.432 us; speedup 1.0000x reference)
//
#include <hip/hip_runtime.h>
#include <math.h>

#define NB 8
#define NA 512
#define NN 64
#define ND 128
#define NF 128
#define NG 25
#define NGA 512

__device__ __forceinline__ float sspf(float v) {
  // shifted softplus: ln(1+e^v) - ln2, stable form
  return fmaxf(v, 0.0f) + log1pf(__expf(-fabsf(v))) - 0.6931471805599453f;
}

// ---------------- x = embedding[atomic_numbers] ----------------
__global__ __launch_bounds__(128) void k_init(const int* __restrict__ zn,
                                              const float* __restrict__ emb,
                                              float* __restrict__ x) {
  const int ba = blockIdx.x;
  x[(size_t)ba * ND + threadIdx.x] = emb[(size_t)zn[ba] * ND + threadIdx.x];
}

// ---------------- chunked GEMM helper ----------------
// 256 threads; thread t: row r = t>>4 (16 rows), cols c0=(t&15)*8.
// acc[8] += inrow[k] * W[k][c0..c0+7], W global row-major [K][128], K % 32 == 0.
__device__ __forceinline__ void fma_k4(const float* sWc, int k4, int c0, float4 iv, float acc[8]) {
  const float ivv[4] = {iv.x, iv.y, iv.z, iv.w};
#pragma unroll
  for (int kk = 0; kk < 4; ++kk) {
    const float* wr = sWc + (k4 + kk) * 128 + c0;
    const float4 w0 = *(const float4*)(wr);
    const float4 w1 = *(const float4*)(wr + 4);
    acc[0] = fmaf(ivv[kk], w0.x, acc[0]);
    acc[1] = fmaf(ivv[kk], w0.y, acc[1]);
    acc[2] = fmaf(ivv[kk], w0.z, acc[2]);
    acc[3] = fmaf(ivv[kk], w0.w, acc[3]);
    acc[4] = fmaf(ivv[kk], w1.x, acc[4]);
    acc[5] = fmaf(ivv[kk], w1.y, acc[5]);
    acc[6] = fmaf(ivv[kk], w1.z, acc[6]);
    acc[7] = fmaf(ivv[kk], w1.w, acc[7]);
  }
}

__device__ __forceinline__ void gemm_chunked(const float* inrow, const float* __restrict__ Wg,
                                             int K, float* sWc, int t, int c0, float acc[8]) {
  for (int kc = 0; kc < K; kc += 32) {
    __syncthreads();
    const float4* src = (const float4*)(Wg + (size_t)kc * 128);
    float4* dst = (float4*)sWc;
#pragma unroll
    for (int i = 0; i < 4; ++i) dst[t + 256 * i] = src[t + 256 * i];
    __syncthreads();
#pragma unroll
    for (int k4 = 0; k4 < 32; k4 += 4) {
      const float4 iv = *(const float4*)(inrow + kc + k4);
      fma_k4(sWc, k4, c0, iv, acc);
    }
  }
}

// K=512 variant that also streams the input rows (G_i) from global in k-chunks.
__device__ __forceinline__ void gemm_ang(const float* __restrict__ Grow0,
                                         const float* __restrict__ Wg,
                                         float* sWc, float* sGc,
                                         int t, int r, int c0, float acc[8]) {
  for (int kc = 0; kc < NGA; kc += 32) {
    __syncthreads();
    const float4* src = (const float4*)(Wg + (size_t)kc * 128);
#pragma unroll
    for (int i = 0; i < 4; ++i) ((float4*)sWc)[t + 256 * i] = src[t + 256 * i];
    if (t < 128) {
      const int rr = t >> 3, cc = (t & 7) << 2;
      *(float4*)(sGc + rr * 32 + cc) = *(const float4*)(Grow0 + (size_t)rr * NGA + kc + cc);
    }
    __syncthreads();
    const float* inrow = sGc + r * 32;
#pragma unroll
    for (int k4 = 0; k4 < 32; k4 += 4) {
      const float4 iv = *(const float4*)(inrow + k4);
      fma_k4(sWc, k4, c0, iv, acc);
    }
  }
}

// ---------------- y = x @ in2f_w[0] ----------------
__global__ __launch_bounds__(256) void k_lin(const float* __restrict__ in,
                                             const float* __restrict__ Wg,
                                             float* __restrict__ out) {
  __shared__ alignas(16) float sIn[16 * 128];
  __shared__ alignas(16) float sWc[32 * 128];
  const int t = threadIdx.x;
  const int row0 = blockIdx.x * 16;
  const float4* s4 = (const float4*)(in + (size_t)row0 * 128);
#pragma unroll
  for (int i = 0; i < 2; ++i) ((float4*)sIn)[t + 256 * i] = s4[t + 256 * i];
  const int r = t >> 4, c0 = (t & 15) << 3;
  float acc[8] = {0.f, 0.f, 0.f, 0.f, 0.f, 0.f, 0.f, 0.f};
  gemm_chunked(sIn + r * 128, Wg, 128, sWc, t, c0, acc);
  float* o = out + (size_t)(row0 + r) * 128 + c0;
  *(float4*)o = make_float4(acc[0], acc[1], acc[2], acc[3]);
  *(float4*)(o + 4) = make_float4(acc[4], acc[5], acc[6], acc[7]);
}

// ---------------- fused CFConv: one atom per block, 128 threads ----------------
// agg[i][f] = sum_j scale_ij * y[nbr_ij][f] * (b2[f] + sum_k ssp(f_ij@w1+b1)[k] * w2[k][f])
__global__ __launch_bounds__(128, 1) void k_cfconv(
    const float* __restrict__ pos, const int* __restrict__ nbr,
    const int* __restrict__ nmask, const float* __restrict__ y,
    const float* __restrict__ w1, const float* __restrict__ b1,
    const float* __restrict__ w2, const float* __restrict__ b2,
    float* __restrict__ agg) {
  __shared__ alignas(16) float sF[NG * NN];   // gaussians [g][j]
  __shared__ alignas(16) float sH[NN * 128];  // h rows, XOR-swizzled cols; later aliased as sPart
  __shared__ alignas(16) float sWc[32 * 128]; // w1 (25x128) then w2 k-chunks
  __shared__ float sScale[NN];
  __shared__ int sNbr[NN];
  __shared__ float sB1[NF];
  __shared__ float sB2[NF];

  const int t = threadIdx.x;
  const int ga = blockIdx.x;            // global atom index b*A + a
  const int b0 = (ga >> 9) << 9;        // structure base (A = 512)

  sB1[t] = b1[t];
  sB2[t] = b2[t];
  if (t < NN) {
    const int nj = nbr[(size_t)ga * NN + t];
    sNbr[t] = nj;
    const float px = pos[(size_t)ga * 3];
    const float py = pos[(size_t)ga * 3 + 1];
    const float pz = pos[(size_t)ga * 3 + 2];
    const float* pj = pos + (size_t)(b0 + nj) * 3;
    const float dx = pj[0] - px, dy = pj[1] - py, dz = pj[2] - pz;
    const float r = sqrtf(dx * dx + dy * dy + dz * dz + 1e-12f);
    sScale[t] = (r <= 5.0f && nmask[(size_t)ga * NN + t] != 0) ? 1.0f : 0.0f;
    const float step = 3.8f / 24.0f;
    const float coef = -0.5f / (step * step);
#pragma unroll
    for (int g = 0; g < NG; ++g) {
      const float d = r - (1.2f + step * (float)g);
      sF[g * NN + t] = __expf(coef * d * d);
    }
  }
  {
    // stage w1 (25*128 = 3200 floats = 800 float4)
    const float4* wsrc = (const float4*)w1;
    float4* wdst = (float4*)sWc;
#pragma unroll
    for (int i = 0; i < 6; ++i) wdst[t + 128 * i] = wsrc[t + 128 * i];
    if (t < 32) wdst[768 + t] = wsrc[768 + t];
  }
  __syncthreads();

  const int rt = t >> 4;          // 0..7 row group
  const int j0 = rt << 3;         // 8 neighbor-rows per thread
  const int c0 = (t & 15) << 3;   // 8 filter-cols per thread
  const int sw = rt << 2;         // per-row-group XOR swizzle (breaks bank aliasing)

  float acc[8][8];
#pragma unroll
  for (int i = 0; i < 8; ++i)
#pragma unroll
    for (int k = 0; k < 8; ++k) acc[i][k] = 0.0f;

  // phase 1: h = ssp(f @ w1 + b1)
#pragma unroll
  for (int g = 0; g < NG; ++g) {
    const float4 fa = *(const float4*)(sF + g * NN + j0);
    const float4 fb = *(const float4*)(sF + g * NN + j0 + 4);
    const float fv[8] = {fa.x, fa.y, fa.z, fa.w, fb.x, fb.y, fb.z, fb.w};
    const float* wr = sWc + g * 128 + c0;
    const float4 w0 = *(const float4*)(wr);
    const float4 w1v = *(const float4*)(wr + 4);
    const float wv[8] = {w0.x, w0.y, w0.z, w0.w, w1v.x, w1v.y, w1v.z, w1v.w};
#pragma unroll
    for (int ii = 0; ii < 8; ++ii)
#pragma unroll
      for (int ff = 0; ff < 8; ++ff) acc[ii][ff] = fmaf(fv[ii], wv[ff], acc[ii][ff]);
  }
#pragma unroll
  for (int ii = 0; ii < 8; ++ii) {
    float ov[8];
#pragma unroll
    for (int ff = 0; ff < 8; ++ff) ov[ff] = sspf(acc[ii][ff] + sB1[c0 + ff]);
    float* hp = sH + (j0 + ii) * 128;
    *(float4*)(hp + (c0 ^ sw)) = make_float4(ov[0], ov[1], ov[2], ov[3]);
    *(float4*)(hp + ((c0 + 4) ^ sw)) = make_float4(ov[4], ov[5], ov[6], ov[7]);
  }

#pragma unroll
  for (int i = 0; i < 8; ++i)
#pragma unroll
    for (int k = 0; k < 8; ++k) acc[i][k] = 0.0f;

  // phase 2: Wmat = h @ w2 (k in 4 chunks of 32)
  for (int kc = 0; kc < 128; kc += 32) {
    __syncthreads();
    const float4* wsrc = (const float4*)(w2 + (size_t)kc * 128);
#pragma unroll
    for (int i = 0; i < 8; ++i) ((float4*)sWc)[t + 128 * i] = wsrc[t + 128 * i];
    __syncthreads();
#pragma unroll
    for (int k4 = 0; k4 < 32; k4 += 4) {
      const int k = kc + k4;
      float4 hv[8];
#pragma unroll
      for (int ii = 0; ii < 8; ++ii)
        hv[ii] = *(const float4*)(sH + (j0 + ii) * 128 + (k ^ sw));
#pragma unroll
      for (int kk = 0; kk < 4; ++kk) {
        const float* wr = sWc + (k4 + kk) * 128 + c0;
        const float4 w0 = *(const float4*)(wr);
        const float4 w1v = *(const float4*)(wr + 4);
        const float wv[8] = {w0.x, w0.y, w0.z, w0.w, w1v.x, w1v.y, w1v.z, w1v.w};
#pragma unroll
        for (int ii = 0; ii < 8; ++ii) {
          const float hvv = (kk == 0) ? hv[ii].x : (kk == 1) ? hv[ii].y
                          : (kk == 2) ? hv[ii].z : hv[ii].w;
#pragma unroll
          for (int ff = 0; ff < 8; ++ff) acc[ii][ff] = fmaf(hvv, wv[ff], acc[ii][ff]);
        }
      }
    }
  }

  // aggregation: pagg[f] = sum_rows scale * (W + b2) * y[nbr][f]
  float pagg[8];
#pragma unroll
  for (int ff = 0; ff < 8; ++ff) pagg[ff] = 0.0f;
#pragma unroll
  for (int ii = 0; ii < 8; ++ii) {
    const int row = j0 + ii;
    const float sc = sScale[row];
    const float* yrow = y + (size_t)(b0 + sNbr[row]) * NF + c0;
    const float4 y0 = *(const float4*)(yrow);
    const float4 y1 = *(const float4*)(yrow + 4);
    const float yv[8] = {y0.x, y0.y, y0.z, y0.w, y1.x, y1.y, y1.z, y1.w};
#pragma unroll
    for (int ff = 0; ff < 8; ++ff)
      pagg[ff] = fmaf(sc * (acc[ii][ff] + sB2[c0 + ff]), yv[ff], pagg[ff]);
  }
  __syncthreads();                    // sH reads done; safe to alias as sPart
  float* sPart = sH;
  *(float4*)(sPart + rt * 128 + c0) = make_float4(pagg[0], pagg[1], pagg[2], pagg[3]);
  *(float4*)(sPart + rt * 128 + c0 + 4) = make_float4(pagg[4], pagg[5], pagg[6], pagg[7]);
  __syncthreads();
  float s = 0.0f;
#pragma unroll
  for (int rg = 0; rg < 8; ++rg) s += sPart[rg * 128 + t];
  agg[(size_t)ga * NF + t] = s;
}

// ---------------- per-layer update ----------------
// x += ssp((agg@f2out+b)@dense + b + G_i@ang_w); optionally y = x_new @ in2f[l+1]
__global__ __launch_bounds__(256) void k_update(
    float* __restrict__ x, const float* __restrict__ agg,
    const float* __restrict__ Gi,
    const float* __restrict__ f2ow, const float* __restrict__ f2ob,
    const float* __restrict__ dw, const float* __restrict__ db,
    const float* __restrict__ aw, const float* __restrict__ in2f_next,
    float* __restrict__ yout) {
  __shared__ alignas(16) float sA[16 * 128];  // agg tile, then reused for tmp
  __shared__ alignas(16) float sX[16 * 128];
  __shared__ alignas(16) float sWc[32 * 128];
  __shared__ alignas(16) float sGc[16 * 32];
  const int t = threadIdx.x;
  const int row0 = blockIdx.x * 16;
  {
    const float4* a4 = (const float4*)(agg + (size_t)row0 * 128);
    const float4* x4 = (const float4*)(x + (size_t)row0 * 128);
#pragma unroll
    for (int i = 0; i < 2; ++i) {
      ((float4*)sA)[t + 256 * i] = a4[t + 256 * i];
      ((float4*)sX)[t + 256 * i] = x4[t + 256 * i];
    }
  }
  const int r = t >> 4, c0 = (t & 15) << 3;
  float acc[8] = {0, 0, 0, 0, 0, 0, 0, 0};
  gemm_chunked(sA + r * 128, f2ow, 128, sWc, t, c0, acc);
  {
    const float4 b0v = *(const float4*)(f2ob + c0);
    const float4 b1v = *(const float4*)(f2ob + c0 + 4);
    acc[0] += b0v.x; acc[1] += b0v.y; acc[2] += b0v.z; acc[3] += b0v.w;
    acc[4] += b1v.x; acc[5] += b1v.y; acc[6] += b1v.z; acc[7] += b1v.w;
  }
  __syncthreads();   // all reads of sA done -> safe to overwrite with tmp
  *(float4*)(sA + r * 128 + c0) = make_float4(acc[0], acc[1], acc[2], acc[3]);
  *(float4*)(sA + r * 128 + c0 + 4) = make_float4(acc[4], acc[5], acc[6], acc[7]);
  float acc2[8] = {0, 0, 0, 0, 0, 0, 0, 0};
  gemm_chunked(sA + r * 128, dw, 128, sWc, t, c0, acc2);
  gemm_ang(Gi + (size_t)row0 * NGA, aw, sWc, sGc, t, r, c0, acc2);
  float xo[8];
  {
    const float4 d0 = *(const float4*)(db + c0);
    const float4 d1 = *(const float4*)(db + c0 + 4);
    const float dv[8] = {d0.x, d0.y, d0.z, d0.w, d1.x, d1.y, d1.z, d1.w};
#pragma unroll
    for (int i = 0; i < 8; ++i)
      xo[i] = sX[r * 128 + c0 + i] + sspf(acc2[i] + dv[i]);
  }
  float* xrow = x + (size_t)(row0 + r) * 128 + c0;
  *(float4*)xrow = make_float4(xo[0], xo[1], xo[2], xo[3]);
  *(float4*)(xrow + 4) = make_float4(xo[4], xo[5], xo[6], xo[7]);
  if (in2f_next != nullptr) {
    // each thread overwrites exactly the sX elements it read above -> no WAR hazard
    *(float4*)(sX + r * 128 + c0) = make_float4(xo[0], xo[1], xo[2], xo[3]);
    *(float4*)(sX + r * 128 + c0 + 4) = make_float4(xo[4], xo[5], xo[6], xo[7]);
    float acc3[8] = {0, 0, 0, 0, 0, 0, 0, 0};
    gemm_chunked(sX + r * 128, in2f_next, 128, sWc, t, c0, acc3);
    float* yrow = yout + (size_t)(row0 + r) * 128 + c0;
    *(float4*)yrow = make_float4(acc3[0], acc3[1], acc3[2], acc3[3]);
    *(float4*)(yrow + 4) = make_float4(acc3[4], acc3[5], acc3[6], acc3[7]);
  }
}

extern "C" void kernel_launch(void* const* d_in, const int* in_sizes, int n_in,
                              void* d_out, int out_size, void* d_ws, size_t ws_size,
                              hipStream_t stream) {
  (void)in_sizes; (void)n_in; (void)out_size; (void)ws_size;
  const int* zn = (const int*)d_in[0];
  const float* pos = (const float*)d_in[1];
  const int* nbr = (const int*)d_in[2];
  const int* nmask = (const int*)d_in[3];
  const float* Gi = (const float*)d_in[4];
  const float* emb = (const float*)d_in[5];
  const float* fw1 = (const float*)d_in[6];
  const float* fb1 = (const float*)d_in[7];
  const float* fw2 = (const float*)d_in[8];
  const float* fb2 = (const float*)d_in[9];
  const float* in2f = (const float*)d_in[10];
  const float* f2o = (const float*)d_in[11];
  const float* f2ob = (const float*)d_in[12];
  const float* dwp = (const float*)d_in[13];
  const float* dbp = (const float*)d_in[14];
  const float* awp = (const float*)d_in[15];

  float* x = (float*)d_out;                       // [B,A,D] running features
  float* y = (float*)d_ws;                        // [B,A,F]
  float* agg = y + (size_t)NB * NA * NF;          // [B,A,F]

  k_init<<<NB * NA, 128, 0, stream>>>(zn, emb, x);
  k_lin<<<NB * NA / 16, 256, 0, stream>>>(x, in2f, y);
  for (int l = 0; l < 3; ++l) {
    k_cfconv<<<NB * NA, 128, 0, stream>>>(pos, nbr, nmask, y,
        fw1 + (size_t)l * NG * NF, fb1 + (size_t)l * NF,
        fw2 + (size_t)l * NF * NF, fb2 + (size_t)l * NF, agg);
    k_update<<<NB * NA / 16, 256, 0, stream>>>(x, agg, Gi,
        f2o + (size_t)l * NF * ND, f2ob + (size_t)l * ND,
        dwp + (size_t)l * ND * ND, dbp + (size_t)l * ND,
        awp + (size_t)l * NGA * ND,
        (l < 2) ? (in2f + (size_t)(l + 1) * ND * NF) : nullptr, y);
  }
}

// Round 2
// 582.356 us; speedup vs baseline: 1.7059x; 1.7059x over previous
//
#include <hip/hip_runtime.h>
#include <math.h>

#define NB 8
#define NA 512
#define NN 64
#define ND 128
#define NF 128
#define NG 25
#define NGA 512

typedef __attribute__((ext_vector_type(8))) short bf16x8;
typedef __attribute__((ext_vector_type(4))) float f32x4;

__device__ __forceinline__ float sspf(float v) {
  // shifted softplus: ln(1+e^v) - ln2, stable form
  return fmaxf(v, 0.0f) + log1pf(__expf(-fabsf(v))) - 0.6931471805599453f;
}

__device__ __forceinline__ short f2bf(float x) {
  union { float f; unsigned u; } v; v.f = x;
  unsigned r = v.u + 0x7fffu + ((v.u >> 16) & 1u);   // RNE
  return (short)(r >> 16);
}

// ---------------- x = embedding[atomic_numbers] ----------------
__global__ __launch_bounds__(128) void k_init(const int* __restrict__ zn,
                                              const float* __restrict__ emb,
                                              float* __restrict__ x) {
  const int ba = blockIdx.x;
  x[(size_t)ba * ND + threadIdx.x] = emb[(size_t)zn[ba] * ND + threadIdx.x];
}

// ---------------- weight prep: bf16 transposed copies ----------------
// w1T[l][n][k] (k padded 25->32 with zeros), w2T[l][n][k]
__global__ __launch_bounds__(256) void k_prep(const float* __restrict__ fw1,
                                              const float* __restrict__ fw2,
                                              short* __restrict__ w1T,
                                              short* __restrict__ w2T) {
  const int i = blockIdx.x * 256 + threadIdx.x;
  if (i < 3 * 128 * 32) {
    const int l = i >> 12, r = i & 4095, n = r >> 5, k = r & 31;
    w1T[i] = (k < NG) ? f2bf(fw1[(size_t)l * NG * NF + k * NF + n]) : (short)0;
  }
  const int j = i - 3 * 128 * 32;
  if (j >= 0 && j < 3 * 128 * 128) {
    const int l = j >> 14, r = j & 16383, n = r >> 7, k = r & 127;
    w2T[j] = f2bf(fw2[(size_t)l * NF * NF + k * NF + n]);
  }
}

// ---------------- chunked GEMM helper (fp32, for k_lin / k_update) ----------------
__device__ __forceinline__ void fma_k4(const float* sWc, int k4, int c0, float4 iv, float acc[8]) {
  const float ivv[4] = {iv.x, iv.y, iv.z, iv.w};
#pragma unroll
  for (int kk = 0; kk < 4; ++kk) {
    const float* wr = sWc + (k4 + kk) * 128 + c0;
    const float4 w0 = *(const float4*)(wr);
    const float4 w1 = *(const float4*)(wr + 4);
    acc[0] = fmaf(ivv[kk], w0.x, acc[0]);
    acc[1] = fmaf(ivv[kk], w0.y, acc[1]);
    acc[2] = fmaf(ivv[kk], w0.z, acc[2]);
    acc[3] = fmaf(ivv[kk], w0.w, acc[3]);
    acc[4] = fmaf(ivv[kk], w1.x, acc[4]);
    acc[5] = fmaf(ivv[kk], w1.y, acc[5]);
    acc[6] = fmaf(ivv[kk], w1.z, acc[6]);
    acc[7] = fmaf(ivv[kk], w1.w, acc[7]);
  }
}

__device__ __forceinline__ void gemm_chunked(const float* inrow, const float* __restrict__ Wg,
                                             int K, float* sWc, int t, int c0, float acc[8]) {
  for (int kc = 0; kc < K; kc += 32) {
    __syncthreads();
    const float4* src = (const float4*)(Wg + (size_t)kc * 128);
    float4* dst = (float4*)sWc;
#pragma unroll
    for (int i = 0; i < 4; ++i) dst[t + 256 * i] = src[t + 256 * i];
    __syncthreads();
#pragma unroll
    for (int k4 = 0; k4 < 32; k4 += 4) {
      const float4 iv = *(const float4*)(inrow + kc + k4);
      fma_k4(sWc, k4, c0, iv, acc);
    }
  }
}

__device__ __forceinline__ void gemm_ang(const float* __restrict__ Grow0,
                                         const float* __restrict__ Wg,
                                         float* sWc, float* sGc,
                                         int t, int r, int c0, float acc[8]) {
  for (int kc = 0; kc < NGA; kc += 32) {
    __syncthreads();
    const float4* src = (const float4*)(Wg + (size_t)kc * 128);
#pragma unroll
    for (int i = 0; i < 4; ++i) ((float4*)sWc)[t + 256 * i] = src[t + 256 * i];
    if (t < 128) {
      const int rr = t >> 3, cc = (t & 7) << 2;
      *(float4*)(sGc + rr * 32 + cc) = *(const float4*)(Grow0 + (size_t)rr * NGA + kc + cc);
    }
    __syncthreads();
    const float* inrow = sGc + r * 32;
#pragma unroll
    for (int k4 = 0; k4 < 32; k4 += 4) {
      const float4 iv = *(const float4*)(inrow + k4);
      fma_k4(sWc, k4, c0, iv, acc);
    }
  }
}

// ---------------- y = x @ in2f_w[0] ----------------
__global__ __launch_bounds__(256) void k_lin(const float* __restrict__ in,
                                             const float* __restrict__ Wg,
                                             float* __restrict__ out) {
  __shared__ alignas(16) float sIn[16 * 128];
  __shared__ alignas(16) float sWc[32 * 128];
  const int t = threadIdx.x;
  const int row0 = blockIdx.x * 16;
  const float4* s4 = (const float4*)(in + (size_t)row0 * 128);
#pragma unroll
  for (int i = 0; i < 2; ++i) ((float4*)sIn)[t + 256 * i] = s4[t + 256 * i];
  const int r = t >> 4, c0 = (t & 15) << 3;
  float acc[8] = {0.f, 0.f, 0.f, 0.f, 0.f, 0.f, 0.f, 0.f};
  gemm_chunked(sIn + r * 128, Wg, 128, sWc, t, c0, acc);
  float* o = out + (size_t)(row0 + r) * 128 + c0;
  *(float4*)o = make_float4(acc[0], acc[1], acc[2], acc[3]);
  *(float4*)(o + 4) = make_float4(acc[4], acc[5], acc[6], acc[7]);
}

// ---------------- fused CFConv with MFMA filter network ----------------
// one atom per block, 128 threads = 2 waves; wave w owns output cols [w*64, w*64+64)
// phase1: h = ssp(f @ w1 + b1)   f:[64x32pad] bf16 (LDS), w1T B-frags in regs
// phase2: W = h @ w2 ; agg[f] = sum_j scale_j*(W[j][f]+b2[f])*y[nbr_j][f]
#define HPAD 136   // sH row stride (bf16 elems): 272B = 68 words -> 2-way bank alias (free)
#define FPAD 40    // sFT row stride: 80B, 16B aligned
__global__ __launch_bounds__(128) void k_cfconv(
    const float* __restrict__ pos, const int* __restrict__ nbr,
    const int* __restrict__ nmask, const float* __restrict__ y,
    const short* __restrict__ w1T, const float* __restrict__ b1,
    const short* __restrict__ w2T, const float* __restrict__ b2,
    float* __restrict__ agg) {
  __shared__ alignas(16) short sFT[NN * FPAD];   // f^T rows [j][k<=32]
  __shared__ alignas(16) short sH[NN * HPAD];    // h rows [j][k=128] bf16
  __shared__ float sScale[NN];
  __shared__ int sNbr[NN];
  __shared__ float sB1[NF];
  __shared__ float sB2[NF];
  __shared__ float sPart[4 * NF];

  const int t = threadIdx.x;
  const int ga = blockIdx.x;
  const int b0 = ga & ~(NA - 1);
  const int lane = t & 63;
  const int wave = t >> 6;
  const int lanelo = lane & 15;
  const int quad = lane >> 4;
  const int wbase = wave << 6;           // this wave's col offset (0 or 64)

  sB1[t] = b1[t];
  sB2[t] = b2[t];

  // B-fragments from prepped global bf16 (issue loads early; broadcast across blocks -> L2)
  bf16x8 bw1[4];
  bf16x8 bw2[16];
#pragma unroll
  for (int ct = 0; ct < 4; ++ct) {
    const int n = wbase + ct * 16 + lanelo;
    bw1[ct] = *(const bf16x8*)(w1T + n * 32 + quad * 8);
#pragma unroll
    for (int kt = 0; kt < 4; ++kt)
      bw2[ct * 4 + kt] = *(const bf16x8*)(w2T + n * 128 + kt * 32 + quad * 8);
  }

  if (t < NN) {
    const int nj = nbr[(size_t)ga * NN + t];
    sNbr[t] = nj;
    const float px = pos[(size_t)ga * 3];
    const float py = pos[(size_t)ga * 3 + 1];
    const float pz = pos[(size_t)ga * 3 + 2];
    const float* pj = pos + (size_t)(b0 + nj) * 3;
    const float dx = pj[0] - px, dy = pj[1] - py, dz = pj[2] - pz;
    const float r = sqrtf(dx * dx + dy * dy + dz * dz + 1e-12f);
    sScale[t] = (r <= 5.0f && nmask[(size_t)ga * NN + t] != 0) ? 1.0f : 0.0f;
    const float step = 3.8f / 24.0f;
    const float coef = -0.5f / (step * step);
    short* fr = sFT + t * FPAD;
#pragma unroll
    for (int g = 0; g < NG; ++g) {
      const float d = r - (1.2f + step * (float)g);
      fr[g] = f2bf(__expf(coef * d * d));
    }
#pragma unroll
    for (int g = NG; g < 32; ++g) fr[g] = 0;
  }
  __syncthreads();

  // ---- phase 1: h = ssp(f @ w1 + b1), stored bf16 to sH ----
#pragma unroll
  for (int rt = 0; rt < 4; ++rt) {
    const bf16x8 a = *(const bf16x8*)(sFT + (rt * 16 + lanelo) * FPAD + quad * 8);
#pragma unroll
    for (int ct = 0; ct < 4; ++ct) {
      f32x4 c = {0.f, 0.f, 0.f, 0.f};
      c = __builtin_amdgcn_mfma_f32_16x16x32_bf16(a, bw1[ct], c, 0, 0, 0);
      const int f = wbase + ct * 16 + lanelo;
      const float b1f = sB1[f];
#pragma unroll
      for (int reg = 0; reg < 4; ++reg) {
        const int j = rt * 16 + quad * 4 + reg;
        sH[j * HPAD + f] = f2bf(sspf(c[reg] + b1f));
      }
    }
  }
  __syncthreads();

  // ---- phase 2: W = h @ w2, consumed in-register against y gathers ----
  float pagg[4] = {0.f, 0.f, 0.f, 0.f};
#pragma unroll
  for (int rt = 0; rt < 4; ++rt) {
    f32x4 acc[4];
#pragma unroll
    for (int ct = 0; ct < 4; ++ct) acc[ct] = (f32x4){0.f, 0.f, 0.f, 0.f};
#pragma unroll
    for (int kt = 0; kt < 4; ++kt) {
      const bf16x8 a = *(const bf16x8*)(sH + (rt * 16 + lanelo) * HPAD + kt * 32 + quad * 8);
#pragma unroll
      for (int ct = 0; ct < 4; ++ct)
        acc[ct] = __builtin_amdgcn_mfma_f32_16x16x32_bf16(a, bw2[ct * 4 + kt], acc[ct], 0, 0, 0);
    }
#pragma unroll
    for (int ct = 0; ct < 4; ++ct) {
      const int f = wbase + ct * 16 + lanelo;
      const float b2f = sB2[f];
#pragma unroll
      for (int reg = 0; reg < 4; ++reg) {
        const int j = rt * 16 + quad * 4 + reg;
        const float sc = sScale[j];
        const int nj = sNbr[j];
        pagg[ct] = fmaf(sc * (acc[ct][reg] + b2f), y[(size_t)(b0 + nj) * NF + f], pagg[ct]);
      }
    }
  }

  // ---- quad reduction ----
#pragma unroll
  for (int ct = 0; ct < 4; ++ct)
    sPart[quad * NF + wbase + ct * 16 + lanelo] = pagg[ct];
  __syncthreads();
  agg[(size_t)ga * NF + t] = sPart[t] + sPart[NF + t] + sPart[2 * NF + t] + sPart[3 * NF + t];
}

// ---------------- per-layer update ----------------
__global__ __launch_bounds__(256) void k_update(
    float* __restrict__ x, const float* __restrict__ agg,
    const float* __restrict__ Gi,
    const float* __restrict__ f2ow, const float* __restrict__ f2ob,
    const float* __restrict__ dw, const float* __restrict__ db,
    const float* __restrict__ aw, const float* __restrict__ in2f_next,
    float* __restrict__ yout) {
  __shared__ alignas(16) float sA[16 * 128];
  __shared__ alignas(16) float sX[16 * 128];
  __shared__ alignas(16) float sWc[32 * 128];
  __shared__ alignas(16) float sGc[16 * 32];
  const int t = threadIdx.x;
  const int row0 = blockIdx.x * 16;
  {
    const float4* a4 = (const float4*)(agg + (size_t)row0 * 128);
    const float4* x4 = (const float4*)(x + (size_t)row0 * 128);
#pragma unroll
    for (int i = 0; i < 2; ++i) {
      ((float4*)sA)[t + 256 * i] = a4[t + 256 * i];
      ((float4*)sX)[t + 256 * i] = x4[t + 256 * i];
    }
  }
  const int r = t >> 4, c0 = (t & 15) << 3;
  float acc[8] = {0, 0, 0, 0, 0, 0, 0, 0};
  gemm_chunked(sA + r * 128, f2ow, 128, sWc, t, c0, acc);
  {
    const float4 b0v = *(const float4*)(f2ob + c0);
    const float4 b1v = *(const float4*)(f2ob + c0 + 4);
    acc[0] += b0v.x; acc[1] += b0v.y; acc[2] += b0v.z; acc[3] += b0v.w;
    acc[4] += b1v.x; acc[5] += b1v.y; acc[6] += b1v.z; acc[7] += b1v.w;
  }
  __syncthreads();
  *(float4*)(sA + r * 128 + c0) = make_float4(acc[0], acc[1], acc[2], acc[3]);
  *(float4*)(sA + r * 128 + c0 + 4) = make_float4(acc[4], acc[5], acc[6], acc[7]);
  float acc2[8] = {0, 0, 0, 0, 0, 0, 0, 0};
  gemm_chunked(sA + r * 128, dw, 128, sWc, t, c0, acc2);
  gemm_ang(Gi + (size_t)row0 * NGA, aw, sWc, sGc, t, r, c0, acc2);
  float xo[8];
  {
    const float4 d0 = *(const float4*)(db + c0);
    const float4 d1 = *(const float4*)(db + c0 + 4);
    const float dv[8] = {d0.x, d0.y, d0.z, d0.w, d1.x, d1.y, d1.z, d1.w};
#pragma unroll
    for (int i = 0; i < 8; ++i)
      xo[i] = sX[r * 128 + c0 + i] + sspf(acc2[i] + dv[i]);
  }
  float* xrow = x + (size_t)(row0 + r) * 128 + c0;
  *(float4*)xrow = make_float4(xo[0], xo[1], xo[2], xo[3]);
  *(float4*)(xrow + 4) = make_float4(xo[4], xo[5], xo[6], xo[7]);
  if (in2f_next != nullptr) {
    *(float4*)(sX + r * 128 + c0) = make_float4(xo[0], xo[1], xo[2], xo[3]);
    *(float4*)(sX + r * 128 + c0 + 4) = make_float4(xo[4], xo[5], xo[6], xo[7]);
    float acc3[8] = {0, 0, 0, 0, 0, 0, 0, 0};
    gemm_chunked(sX + r * 128, in2f_next, 128, sWc, t, c0, acc3);
    float* yrow = yout + (size_t)(row0 + r) * 128 + c0;
    *(float4*)yrow = make_float4(acc3[0], acc3[1], acc3[2], acc3[3]);
    *(float4*)(yrow + 4) = make_float4(acc3[4], acc3[5], acc3[6], acc3[7]);
  }
}

extern "C" void kernel_launch(void* const* d_in, const int* in_sizes, int n_in,
                              void* d_out, int out_size, void* d_ws, size_t ws_size,
                              hipStream_t stream) {
  (void)in_sizes; (void)n_in; (void)out_size; (void)ws_size;
  const int* zn = (const int*)d_in[0];
  const float* pos = (const float*)d_in[1];
  const int* nbr = (const int*)d_in[2];
  const int* nmask = (const int*)d_in[3];
  const float* Gi = (const float*)d_in[4];
  const float* emb = (const float*)d_in[5];
  const float* fw1 = (const float*)d_in[6];
  const float* fb1 = (const float*)d_in[7];
  const float* fw2 = (const float*)d_in[8];
  const float* fb2 = (const float*)d_in[9];
  const float* in2f = (const float*)d_in[10];
  const float* f2o = (const float*)d_in[11];
  const float* f2ob = (const float*)d_in[12];
  const float* dwp = (const float*)d_in[13];
  const float* dbp = (const float*)d_in[14];
  const float* awp = (const float*)d_in[15];

  float* x = (float*)d_out;                         // [B,A,D]
  float* y = (float*)d_ws;                          // [B,A,F] fp32
  float* agg = y + (size_t)NB * NA * NF;            // [B,A,F] fp32
  short* w1T = (short*)(agg + (size_t)NB * NA * NF);// [3][128][32] bf16
  short* w2T = w1T + 3 * 128 * 32;                  // [3][128][128] bf16

  k_prep<<<(3 * 128 * 32 + 3 * 128 * 128 + 255) / 256, 256, 0, stream>>>(fw1, fw2, w1T, w2T);
  k_init<<<NB * NA, 128, 0, stream>>>(zn, emb, x);
  k_lin<<<NB * NA / 16, 256, 0, stream>>>(x, in2f, y);
  for (int l = 0; l < 3; ++l) {
    k_cfconv<<<NB * NA, 128, 0, stream>>>(pos, nbr, nmask, y,
        w1T + (size_t)l * 128 * 32, fb1 + (size_t)l * NF,
        w2T + (size_t)l * 128 * 128, fb2 + (size_t)l * NF, agg);
    k_update<<<NB * NA / 16, 256, 0, stream>>>(x, agg, Gi,
        f2o + (size_t)l * NF * ND, f2ob + (size_t)l * ND,
        dwp + (size_t)l * ND * ND, dbp + (size_t)l * ND,
        awp + (size_t)l * NGA * ND,
        (l < 2) ? (in2f + (size_t)(l + 1) * ND * NF) : nullptr, y);
  }
}

// Round 3
// 264.995 us; speedup vs baseline: 3.7489x; 2.1976x over previous
//
#include <hip/hip_runtime.h>
#include <math.h>

#define NB 8
#define NA 512
#define NN 64
#define ND 128
#define NF 128
#define NG 25
#define NGA 512

typedef __attribute__((ext_vector_type(8))) short bf16x8;
typedef __attribute__((ext_vector_type(4))) float f32x4;

__device__ __forceinline__ float sspf(float v) {
  // shifted softplus via HW exp/log: max(v,0) + log(1+exp(-|v|)) - ln2
  return fmaxf(v, 0.0f) + __logf(1.0f + __expf(-fabsf(v))) - 0.6931471805599453f;
}

__device__ __forceinline__ short f2bf(float x) {
  union { float f; unsigned u; } v; v.f = x;
  unsigned r = v.u + 0x7fffu + ((v.u >> 16) & 1u);   // RNE
  return (short)(r >> 16);
}

// ---------------- x = embedding[atomic_numbers] (fp32 + bf16 copy) ----------------
__global__ __launch_bounds__(128) void k_init(const int* __restrict__ zn,
                                              const float* __restrict__ emb,
                                              float* __restrict__ x,
                                              short* __restrict__ xB) {
  const int ba = blockIdx.x;
  const float v = emb[(size_t)zn[ba] * ND + threadIdx.x];
  x[(size_t)ba * ND + threadIdx.x] = v;
  xB[(size_t)ba * ND + threadIdx.x] = f2bf(v);
}

// ---------------- prep: bf16 (transposed) copies of everything GEMM-shaped ----------
#define NGI (NB * NA * NGA)      // 2097152
#define NW1 (3 * 128 * 32)       // 12288
#define NSQ (3 * 128 * 128)      // 49152
#define NAW (3 * 128 * 512)      // 196608
__global__ __launch_bounds__(256) void k_prep(
    const float* __restrict__ Gi, const float* __restrict__ fw1,
    const float* __restrict__ fw2, const float* __restrict__ in2f,
    const float* __restrict__ f2o, const float* __restrict__ dw,
    const float* __restrict__ aw,
    short* __restrict__ GiB, short* __restrict__ w1T, short* __restrict__ w2T,
    short* __restrict__ in2fT, short* __restrict__ f2oT, short* __restrict__ dwT,
    short* __restrict__ awT) {
  int idx = blockIdx.x * 256 + threadIdx.x;
  if (idx < NGI) { GiB[idx] = f2bf(Gi[idx]); return; }
  idx -= NGI;
  if (idx < NW1) {
    const int l = idx >> 12, r = idx & 4095, n = r >> 5, k = r & 31;
    w1T[idx] = (k < NG) ? f2bf(fw1[(size_t)l * NG * NF + k * NF + n]) : (short)0;
    return;
  }
  idx -= NW1;
  if (idx < 4 * NSQ) {
    const int which = idx / NSQ, q = idx % NSQ;
    const int l = q >> 14, r = q & 16383, n = r >> 7, k = r & 127;
    const float* src = (which == 0) ? fw2 : (which == 1) ? in2f : (which == 2) ? f2o : dw;
    short* dst = (which == 0) ? w2T : (which == 1) ? in2fT : (which == 2) ? f2oT : dwT;
    dst[q] = f2bf(src[(size_t)l * 16384 + k * 128 + n]);
    return;
  }
  idx -= 4 * NSQ;
  if (idx < NAW) {
    const int l = idx >> 16, r = idx & 65535, n = r >> 9, k = r & 511;
    awT[idx] = f2bf(aw[(size_t)l * 65536 + k * 128 + n]);
  }
}

// ---------------- y = xB @ in2fT[0]  (MFMA, 16 rows/block) ----------------
__global__ __launch_bounds__(256) void k_lin(const short* __restrict__ xB,
                                             const short* __restrict__ WT,
                                             float* __restrict__ y) {
  const int t = threadIdx.x;
  const int lane = t & 63, wave = t >> 6;
  const int lanelo = lane & 15, quad = lane >> 4;
  const int wbase = wave << 5;
  const int row0 = blockIdx.x << 4;
  f32x4 c[2] = {{0.f, 0.f, 0.f, 0.f}, {0.f, 0.f, 0.f, 0.f}};
#pragma unroll
  for (int kt = 0; kt < 4; ++kt) {
    const bf16x8 a = *(const bf16x8*)(xB + (size_t)(row0 + lanelo) * 128 + kt * 32 + quad * 8);
#pragma unroll
    for (int ct = 0; ct < 2; ++ct) {
      const int n = wbase + ct * 16 + lanelo;
      const bf16x8 b = *(const bf16x8*)(WT + n * 128 + kt * 32 + quad * 8);
      c[ct] = __builtin_amdgcn_mfma_f32_16x16x32_bf16(a, b, c[ct], 0, 0, 0);
    }
  }
#pragma unroll
  for (int ct = 0; ct < 2; ++ct) {
    const int col = wbase + ct * 16 + lanelo;
#pragma unroll
    for (int reg = 0; reg < 4; ++reg)
      y[(size_t)(row0 + quad * 4 + reg) * 128 + col] = c[ct][reg];
  }
}

// ---------------- fused CFConv with MFMA filter network ----------------
#define HPAD 136
#define FPAD 40
__global__ __launch_bounds__(128) void k_cfconv(
    const float* __restrict__ pos, const int* __restrict__ nbr,
    const int* __restrict__ nmask, const float* __restrict__ y,
    const short* __restrict__ w1T, const float* __restrict__ b1,
    const short* __restrict__ w2T, const float* __restrict__ b2,
    short* __restrict__ aggB) {
  __shared__ alignas(16) short sFT[NN * FPAD];
  __shared__ alignas(16) short sH[NN * HPAD];
  __shared__ float sScale[NN];
  __shared__ int sNbr[NN];
  __shared__ float sB1[NF];
  __shared__ float sB2[NF];
  __shared__ float sPart[4 * NF];

  const int t = threadIdx.x;
  const int ga = blockIdx.x;
  const int b0 = ga & ~(NA - 1);
  const int lane = t & 63;
  const int wave = t >> 6;
  const int lanelo = lane & 15;
  const int quad = lane >> 4;
  const int wbase = wave << 6;

  sB1[t] = b1[t];
  sB2[t] = b2[t];

  bf16x8 bw1[4];
  bf16x8 bw2[16];
#pragma unroll
  for (int ct = 0; ct < 4; ++ct) {
    const int n = wbase + ct * 16 + lanelo;
    bw1[ct] = *(const bf16x8*)(w1T + n * 32 + quad * 8);
#pragma unroll
    for (int kt = 0; kt < 4; ++kt)
      bw2[ct * 4 + kt] = *(const bf16x8*)(w2T + n * 128 + kt * 32 + quad * 8);
  }

  if (t < NN) {
    const int nj = nbr[(size_t)ga * NN + t];
    sNbr[t] = nj;
    const float px = pos[(size_t)ga * 3];
    const float py = pos[(size_t)ga * 3 + 1];
    const float pz = pos[(size_t)ga * 3 + 2];
    const float* pj = pos + (size_t)(b0 + nj) * 3;
    const float dx = pj[0] - px, dy = pj[1] - py, dz = pj[2] - pz;
    const float r = sqrtf(dx * dx + dy * dy + dz * dz + 1e-12f);
    sScale[t] = (r <= 5.0f && nmask[(size_t)ga * NN + t] != 0) ? 1.0f : 0.0f;
    const float step = 3.8f / 24.0f;
    const float coef = -0.5f / (step * step);
    short* fr = sFT + t * FPAD;
#pragma unroll
    for (int g = 0; g < NG; ++g) {
      const float d = r - (1.2f + step * (float)g);
      fr[g] = f2bf(__expf(coef * d * d));
    }
#pragma unroll
    for (int g = NG; g < 32; ++g) fr[g] = 0;
  }
  __syncthreads();

  // phase 1: h = ssp(f @ w1 + b1) -> bf16 LDS
#pragma unroll
  for (int rt = 0; rt < 4; ++rt) {
    const bf16x8 a = *(const bf16x8*)(sFT + (rt * 16 + lanelo) * FPAD + quad * 8);
#pragma unroll
    for (int ct = 0; ct < 4; ++ct) {
      f32x4 c = {0.f, 0.f, 0.f, 0.f};
      c = __builtin_amdgcn_mfma_f32_16x16x32_bf16(a, bw1[ct], c, 0, 0, 0);
      const int f = wbase + ct * 16 + lanelo;
      const float b1f = sB1[f];
#pragma unroll
      for (int reg = 0; reg < 4; ++reg) {
        const int j = rt * 16 + quad * 4 + reg;
        sH[j * HPAD + f] = f2bf(sspf(c[reg] + b1f));
      }
    }
  }
  __syncthreads();

  // phase 2: W = h @ w2, consumed in-register against y gathers
  float pagg[4] = {0.f, 0.f, 0.f, 0.f};
#pragma unroll
  for (int rt = 0; rt < 4; ++rt) {
    f32x4 acc[4];
#pragma unroll
    for (int ct = 0; ct < 4; ++ct) acc[ct] = (f32x4){0.f, 0.f, 0.f, 0.f};
#pragma unroll
    for (int kt = 0; kt < 4; ++kt) {
      const bf16x8 a = *(const bf16x8*)(sH + (rt * 16 + lanelo) * HPAD + kt * 32 + quad * 8);
#pragma unroll
      for (int ct = 0; ct < 4; ++ct)
        acc[ct] = __builtin_amdgcn_mfma_f32_16x16x32_bf16(a, bw2[ct * 4 + kt], acc[ct], 0, 0, 0);
    }
#pragma unroll
    for (int ct = 0; ct < 4; ++ct) {
      const int f = wbase + ct * 16 + lanelo;
      const float b2f = sB2[f];
#pragma unroll
      for (int reg = 0; reg < 4; ++reg) {
        const int j = rt * 16 + quad * 4 + reg;
        const float sc = sScale[j];
        const int nj = sNbr[j];
        pagg[ct] = fmaf(sc * (acc[ct][reg] + b2f), y[(size_t)(b0 + nj) * NF + f], pagg[ct]);
      }
    }
  }

#pragma unroll
  for (int ct = 0; ct < 4; ++ct)
    sPart[quad * NF + wbase + ct * 16 + lanelo] = pagg[ct];
  __syncthreads();
  aggB[(size_t)ga * NF + t] =
      f2bf(sPart[t] + sPart[NF + t] + sPart[2 * NF + t] + sPart[3 * NF + t]);
}

// ---------------- per-layer update (all-MFMA) ----------------
// t1 = aggB@f2oT + b; v = t1@dwT + db + GiB@awT; x += ssp(v); y = x_new@in2fT
#define TPAD 136
__global__ __launch_bounds__(256) void k_upd(
    float* __restrict__ x, const short* __restrict__ aggB,
    const short* __restrict__ GiB,
    const short* __restrict__ f2oT, const float* __restrict__ f2ob,
    const short* __restrict__ dwT, const float* __restrict__ db,
    const short* __restrict__ awT, const short* __restrict__ in2fT,
    float* __restrict__ yout) {
  __shared__ alignas(16) short sT[16 * TPAD];
  const int t = threadIdx.x;
  const int lane = t & 63, wave = t >> 6;
  const int lanelo = lane & 15, quad = lane >> 4;
  const int wbase = wave << 5;               // 4 waves x 32 cols
  const int row0 = blockIdx.x << 4;

  // GEMM1: t1 = aggB @ f2oT + f2ob  -> bf16 LDS
  f32x4 c1[2] = {{0.f, 0.f, 0.f, 0.f}, {0.f, 0.f, 0.f, 0.f}};
#pragma unroll
  for (int kt = 0; kt < 4; ++kt) {
    const bf16x8 a = *(const bf16x8*)(aggB + (size_t)(row0 + lanelo) * 128 + kt * 32 + quad * 8);
#pragma unroll
    for (int ct = 0; ct < 2; ++ct) {
      const int n = wbase + ct * 16 + lanelo;
      const bf16x8 b = *(const bf16x8*)(f2oT + n * 128 + kt * 32 + quad * 8);
      c1[ct] = __builtin_amdgcn_mfma_f32_16x16x32_bf16(a, b, c1[ct], 0, 0, 0);
    }
  }
#pragma unroll
  for (int ct = 0; ct < 2; ++ct) {
    const int col = wbase + ct * 16 + lanelo;
    const float bv = f2ob[col];
#pragma unroll
    for (int reg = 0; reg < 4; ++reg)
      sT[(quad * 4 + reg) * TPAD + col] = f2bf(c1[ct][reg] + bv);
  }
  __syncthreads();

  // GEMM2 (t1@dwT, K=128) + GEMM3 (GiB@awT, K=512)
  f32x4 c2[2] = {{0.f, 0.f, 0.f, 0.f}, {0.f, 0.f, 0.f, 0.f}};
#pragma unroll
  for (int kt = 0; kt < 4; ++kt) {
    const bf16x8 a = *(const bf16x8*)(sT + lanelo * TPAD + kt * 32 + quad * 8);
#pragma unroll
    for (int ct = 0; ct < 2; ++ct) {
      const int n = wbase + ct * 16 + lanelo;
      const bf16x8 b = *(const bf16x8*)(dwT + n * 128 + kt * 32 + quad * 8);
      c2[ct] = __builtin_amdgcn_mfma_f32_16x16x32_bf16(a, b, c2[ct], 0, 0, 0);
    }
  }
#pragma unroll
  for (int kt = 0; kt < 16; ++kt) {
    const bf16x8 a = *(const bf16x8*)(GiB + (size_t)(row0 + lanelo) * NGA + kt * 32 + quad * 8);
#pragma unroll
    for (int ct = 0; ct < 2; ++ct) {
      const int n = wbase + ct * 16 + lanelo;
      const bf16x8 b = *(const bf16x8*)(awT + n * NGA + kt * 32 + quad * 8);
      c2[ct] = __builtin_amdgcn_mfma_f32_16x16x32_bf16(a, b, c2[ct], 0, 0, 0);
    }
  }
  __syncthreads();   // sT reads done

  // epilogue: x += ssp(v); stage x_new bf16 for GEMM4
#pragma unroll
  for (int ct = 0; ct < 2; ++ct) {
    const int col = wbase + ct * 16 + lanelo;
    const float dbv = db[col];
#pragma unroll
    for (int reg = 0; reg < 4; ++reg) {
      const int row = quad * 4 + reg;
      const size_t g = (size_t)(row0 + row) * 128 + col;
      const float xo = x[g] + sspf(c2[ct][reg] + dbv);
      x[g] = xo;
      if (in2fT != nullptr) sT[row * TPAD + col] = f2bf(xo);
    }
  }
  if (in2fT == nullptr) return;
  __syncthreads();

  // GEMM4: y = x_new @ in2fT
  f32x4 c3[2] = {{0.f, 0.f, 0.f, 0.f}, {0.f, 0.f, 0.f, 0.f}};
#pragma unroll
  for (int kt = 0; kt < 4; ++kt) {
    const bf16x8 a = *(const bf16x8*)(sT + lanelo * TPAD + kt * 32 + quad * 8);
#pragma unroll
    for (int ct = 0; ct < 2; ++ct) {
      const int n = wbase + ct * 16 + lanelo;
      const bf16x8 b = *(const bf16x8*)(in2fT + n * 128 + kt * 32 + quad * 8);
      c3[ct] = __builtin_amdgcn_mfma_f32_16x16x32_bf16(a, b, c3[ct], 0, 0, 0);
    }
  }
#pragma unroll
  for (int ct = 0; ct < 2; ++ct) {
    const int col = wbase + ct * 16 + lanelo;
#pragma unroll
    for (int reg = 0; reg < 4; ++reg)
      yout[(size_t)(row0 + quad * 4 + reg) * 128 + col] = c3[ct][reg];
  }
}

extern "C" void kernel_launch(void* const* d_in, const int* in_sizes, int n_in,
                              void* d_out, int out_size, void* d_ws, size_t ws_size,
                              hipStream_t stream) {
  (void)in_sizes; (void)n_in; (void)out_size; (void)ws_size;
  const int* zn = (const int*)d_in[0];
  const float* pos = (const float*)d_in[1];
  const int* nbr = (const int*)d_in[2];
  const int* nmask = (const int*)d_in[3];
  const float* Gi = (const float*)d_in[4];
  const float* emb = (const float*)d_in[5];
  const float* fw1 = (const float*)d_in[6];
  const float* fb1 = (const float*)d_in[7];
  const float* fw2 = (const float*)d_in[8];
  const float* fb2 = (const float*)d_in[9];
  const float* in2f = (const float*)d_in[10];
  const float* f2o = (const float*)d_in[11];
  const float* f2ob = (const float*)d_in[12];
  const float* dwp = (const float*)d_in[13];
  const float* dbp = (const float*)d_in[14];
  const float* awp = (const float*)d_in[15];

  float* x = (float*)d_out;                          // [B,A,D] fp32
  float* y = (float*)d_ws;                           // [B,A,F] fp32
  short* aggB = (short*)(y + (size_t)NB * NA * NF);  // [B,A,F] bf16
  short* xB = aggB + (size_t)NB * NA * NF;           // [B,A,D] bf16
  short* GiB = xB + (size_t)NB * NA * ND;            // [B,A,GA] bf16
  short* w1T = GiB + (size_t)NGI;                    // [3][128][32]
  short* w2T = w1T + NW1;                            // [3][128][128]
  short* in2fT = w2T + NSQ;
  short* f2oT = in2fT + NSQ;
  short* dwT = f2oT + NSQ;
  short* awT = dwT + NSQ;                            // [3][128][512]

  const int prep_total = NGI + NW1 + 4 * NSQ + NAW;
  k_prep<<<(prep_total + 255) / 256, 256, 0, stream>>>(
      Gi, fw1, fw2, in2f, f2o, dwp, awp, GiB, w1T, w2T, in2fT, f2oT, dwT, awT);
  k_init<<<NB * NA, 128, 0, stream>>>(zn, emb, x, xB);
  k_lin<<<NB * NA / 16, 256, 0, stream>>>(xB, in2fT, y);
  for (int l = 0; l < 3; ++l) {
    k_cfconv<<<NB * NA, 128, 0, stream>>>(pos, nbr, nmask, y,
        w1T + (size_t)l * 128 * 32, fb1 + (size_t)l * NF,
        w2T + (size_t)l * 128 * 128, fb2 + (size_t)l * NF, aggB);
    k_upd<<<NB * NA / 16, 256, 0, stream>>>(x, aggB, GiB,
        f2oT + (size_t)l * NSQ / 3, f2ob + (size_t)l * ND,
        dwT + (size_t)l * NSQ / 3, dbp + (size_t)l * ND,
        awT + (size_t)l * NAW / 3,
        (l < 2) ? (in2fT + (size_t)(l + 1) * NSQ / 3) : nullptr, y);
  }
}